// Round 4
// baseline (174.128 us; speedup 1.0000x reference)
//
#include <hip/hip_runtime.h>
#include <stdint.h>

// B=256, T=512, f32 tensors. Two bf16-MFMA GEMMs per 16-token tile.
// v4: 1 tile/wave (2048 blocks), B1 in VGPRs, one-hot/bias in epilogue,
// 43.3 KB LDS -> 3 blocks/CU, __launch_bounds__(256,3) -> 12 waves/CU.
#define NTOK (256 * 512)
#define TPB 256

typedef short bf16x8 __attribute__((ext_vector_type(8)));
typedef float f32x4 __attribute__((ext_vector_type(4)));
typedef unsigned short u16;
typedef unsigned int u32;

__device__ __forceinline__ u16 f2bf(float f) {
    u32 u = __float_as_uint(f);
    return (u16)((u + 0x7fffu + ((u >> 16) & 1u)) >> 16);  // rne
}

__global__ __launch_bounds__(256, 3)
void tones_v4(const int* __restrict__ widx, const int* __restrict__ xidx,
              const float* __restrict__ y,
              const float* __restrict__ Wxh, const float* __restrict__ bxh,
              const float* __restrict__ Wwh, const float* __restrict__ bwh,
              const float* __restrict__ Wyh, const float* __restrict__ byh,
              const float* __restrict__ Wconv, const float* __restrict__ bconv,
              const float* __restrict__ Whl, const float* __restrict__ bhl,
              float* __restrict__ out)
{
    // R: B1 bf16 image [chunk<24][n<64][j<8] (24576 B); after frag pickup it is
    //    reused as 4 per-wave A-staging areas (wave w at R + w*3072 u16).
    __shared__ __align__(16) u16 R[12288];
    __shared__ __align__(16) u16 sB2[6208];      // [k-chunk<8][n<97][8]
    __shared__ __align__(16) float sXh[768];     // WxhT [xi<16][n<48]
    __shared__ __align__(16) float sWh[768];     // WwhT [xi<16][n<48]
    __shared__ __align__(16) float sbinit[48];   // bxh+bwh+byh

    const int tid = threadIdx.x;

    // ---- stage B1 image (Wyh channel-interleaved; chunks 22,23 = zeros) ----
    for (int e = tid; e < 12288; e += TPB) {
        int j = e & 7, n = (e >> 3) & 63, chunk = e >> 9;
        int k = chunk * 8 + j;                   // k = 2*d + ch
        float v = (n < 48 && k < 176) ? Wyh[n * 176 + (k & 1) * 88 + (k >> 1)] : 0.0f;
        R[e] = f2bf(v);
    }
    // ---- stage B2 = [WhlT ; bhl ; 0], N padded 88->96 ----
    for (int idx = tid; idx < 64 * 96; idx += TPB) {
        int k = idx / 96, dd = idx - 96 * k;
        float v = 0.0f;
        if (dd < 88) { if (k < 48) v = Whl[dd * 48 + k]; else if (k == 48) v = bhl[dd]; }
        sB2[((k >> 3) * 97 + dd) * 8 + (k & 7)] = f2bf(v);
    }
    // ---- one-hot gather tables (f32) ----
    for (int e = tid; e < 768; e += TPB) {
        int n = e >> 4, xi = e & 15;             // W_xh is [48][16] row-major
        sXh[xi * 48 + n] = Wxh[e];
        sWh[xi * 48 + n] = Wwh[e];
    }
    if (tid < 48) sbinit[tid] = bxh[tid] + bwh[tid] + byh[tid];
    const float wc00 = Wconv[0], wc01 = Wconv[1], wc02 = Wconv[2];
    const float wc10 = Wconv[3], wc11 = Wconv[4], wc12 = Wconv[5];
    const float bc0 = bconv[0], bc1 = bconv[1];
    __syncthreads();

    const int wave = tid >> 6, lane = tid & 63;
    const int q = lane >> 4, c = lane & 15;

    // ---- pick up B1 fragments into registers (shared across the kernel) ----
    bf16x8 B1[6][3];
    #pragma unroll
    for (int ks = 0; ks < 6; ks++)
        #pragma unroll
        for (int nt = 0; nt < 3; nt++)
            B1[ks][nt] = *(const bf16x8*)(R + ((ks * 4 + q) * 64 + nt * 16 + c) * 8);
    __syncthreads();   // all waves done reading B1 before A-staging overwrites R

    u16* sW = R + wave * 3072;                   // this wave's 24-chunk A area
    const int tb = blockIdx.x * 64 + wave * 16;  // 16 tokens per wave

    // ---- conv(1->2ch,k=3,pad=1)+relu -> A-fragment-ordered bf16 in LDS ----
    const float* yrow = y + (size_t)tb * 88;     // 16x88 tile, contiguous
    #pragma unroll
    for (int w = 0; w < 6; w++) {
        int flat = w * 256 + 4 * lane;
        if (flat < 1408) {
            float4 v4 = *(const float4*)(yrow + flat);
            int m = flat / 88;
            int d0 = flat - 88 * m;
            float L  = (d0 == 0)  ? 0.0f : yrow[flat - 1];
            float Rv = (d0 == 84) ? 0.0f : yrow[flat + 4];
            float a0 = L, a1 = v4.x, a2 = v4.y, a3 = v4.z, a4 = v4.w, a5 = Rv;
            float c00 = fmaf(wc00, a0, fmaf(wc01, a1, fmaf(wc02, a2, bc0)));
            float c01 = fmaf(wc00, a1, fmaf(wc01, a2, fmaf(wc02, a3, bc0)));
            float c02 = fmaf(wc00, a2, fmaf(wc01, a3, fmaf(wc02, a4, bc0)));
            float c03 = fmaf(wc00, a3, fmaf(wc01, a4, fmaf(wc02, a5, bc0)));
            float c10 = fmaf(wc10, a0, fmaf(wc11, a1, fmaf(wc12, a2, bc1)));
            float c11 = fmaf(wc10, a1, fmaf(wc11, a2, fmaf(wc12, a3, bc1)));
            float c12 = fmaf(wc10, a2, fmaf(wc11, a3, fmaf(wc12, a4, bc1)));
            float c13 = fmaf(wc10, a3, fmaf(wc11, a4, fmaf(wc12, a5, bc1)));
            uint4 pk;
            pk.x = (u32)f2bf(fmaxf(c00, 0.f)) | ((u32)f2bf(fmaxf(c10, 0.f)) << 16);
            pk.y = (u32)f2bf(fmaxf(c01, 0.f)) | ((u32)f2bf(fmaxf(c11, 0.f)) << 16);
            pk.z = (u32)f2bf(fmaxf(c02, 0.f)) | ((u32)f2bf(fmaxf(c12, 0.f)) << 16);
            pk.w = (u32)f2bf(fmaxf(c03, 0.f)) | ((u32)f2bf(fmaxf(c13, 0.f)) << 16);
            *(uint4*)(sW + ((d0 >> 2) * 16 + m) * 8) = pk;   // chunk = d0>>2 (0..21)
        }
    }
    // zero-pad chunks 22,23 (A=0 x B=0 for the K=192 tail)
    if (lane < 32)
        *(uint4*)(sW + ((22 + (lane >> 4)) * 16 + (lane & 15)) * 8) = make_uint4(0, 0, 0, 0);

    // latent indices for this wave's 4 D-rows (shared by 16 c-lanes -> broadcast)
    int xs[4], wv[4];
    #pragma unroll
    for (int r = 0; r < 4; r++) {
        xs[r] = xidx[tb + q * 4 + r];
        wv[r] = widx[tb + q * 4 + r];
    }

    // ---- GEMM1: h[16x48] = A[16x192] * B1[192x48], acc init = summed biases ----
    float bi0 = sbinit[c], bi1 = sbinit[16 + c], bi2 = sbinit[32 + c];
    f32x4 h0 = {bi0, bi0, bi0, bi0};
    f32x4 h1 = {bi1, bi1, bi1, bi1};
    f32x4 h2 = {bi2, bi2, bi2, bi2};
    #pragma unroll
    for (int ks = 0; ks < 6; ks++) {
        bf16x8 af = *(const bf16x8*)(sW + ((ks * 4 + q) * 16 + c) * 8);
        h0 = __builtin_amdgcn_mfma_f32_16x16x32_bf16(af, B1[ks][0], h0, 0, 0, 0);
        h1 = __builtin_amdgcn_mfma_f32_16x16x32_bf16(af, B1[ks][1], h1, 0, 0, 0);
        h2 = __builtin_amdgcn_mfma_f32_16x16x32_bf16(af, B1[ks][2], h2, 0, 0, 0);
    }

    // ---- epilogue1: + one-hot gathers, relu -> bf16 H (A-frag order, chunks 0..5) ----
    if (lane < 32) {   // chunk 6: bias-one at k2=48; chunk 7: zeros
        uint4 hz = make_uint4((lane < 16) ? 0x3F80u : 0u, 0, 0, 0);
        *(uint4*)(sW + ((6 + q) * 16 + c) * 8) = hz;
    }
    #pragma unroll
    for (int r = 0; r < 4; r++) {
        int row = q * 4 + r;   // D row = token index in tile
        float v0 = h0[r] + sXh[xs[r] * 48 +      c] + sWh[wv[r] * 48 +      c];
        float v1 = h1[r] + sXh[xs[r] * 48 + 16 + c] + sWh[wv[r] * 48 + 16 + c];
        float v2 = h2[r] + sXh[xs[r] * 48 + 32 + c] + sWh[wv[r] * 48 + 32 + c];
        sW[((0 + (c >> 3)) * 16 + row) * 8 + (c & 7)] = f2bf(fmaxf(v0, 0.f));
        sW[((2 + (c >> 3)) * 16 + row) * 8 + (c & 7)] = f2bf(fmaxf(v1, 0.f));
        sW[((4 + (c >> 3)) * 16 + row) * 8 + (c & 7)] = f2bf(fmaxf(v2, 0.f));
    }

    // ---- GEMM2: out[16x88] = H[16x64] * B2[64x96] ----
    f32x4 o0 = {0,0,0,0}, o1 = {0,0,0,0}, o2 = {0,0,0,0};
    f32x4 o3 = {0,0,0,0}, o4 = {0,0,0,0}, o5 = {0,0,0,0};
    #pragma unroll
    for (int ks = 0; ks < 2; ks++) {
        bf16x8 a2f = *(const bf16x8*)(sW + ((ks * 4 + q) * 16 + c) * 8);
        bf16x8 b;
        b = *(const bf16x8*)(sB2 + ((ks * 4 + q) * 97 +  0 + c) * 8);
        o0 = __builtin_amdgcn_mfma_f32_16x16x32_bf16(a2f, b, o0, 0, 0, 0);
        b = *(const bf16x8*)(sB2 + ((ks * 4 + q) * 97 + 16 + c) * 8);
        o1 = __builtin_amdgcn_mfma_f32_16x16x32_bf16(a2f, b, o1, 0, 0, 0);
        b = *(const bf16x8*)(sB2 + ((ks * 4 + q) * 97 + 32 + c) * 8);
        o2 = __builtin_amdgcn_mfma_f32_16x16x32_bf16(a2f, b, o2, 0, 0, 0);
        b = *(const bf16x8*)(sB2 + ((ks * 4 + q) * 97 + 48 + c) * 8);
        o3 = __builtin_amdgcn_mfma_f32_16x16x32_bf16(a2f, b, o3, 0, 0, 0);
        b = *(const bf16x8*)(sB2 + ((ks * 4 + q) * 97 + 64 + c) * 8);
        o4 = __builtin_amdgcn_mfma_f32_16x16x32_bf16(a2f, b, o4, 0, 0, 0);
        b = *(const bf16x8*)(sB2 + ((ks * 4 + q) * 97 + 80 + c) * 8);
        o5 = __builtin_amdgcn_mfma_f32_16x16x32_bf16(a2f, b, o5, 0, 0, 0);
    }

    // ---- store: D row = token (q*4+r), col d = nt*16 + c ----
    float* orow = out + (size_t)(tb + q * 4) * 88;
    #pragma unroll
    for (int r = 0; r < 4; r++) {
        orow[r * 88 +  0 + c] = o0[r];
        orow[r * 88 + 16 + c] = o1[r];
        orow[r * 88 + 32 + c] = o2[r];
        orow[r * 88 + 48 + c] = o3[r];
        orow[r * 88 + 64 + c] = o4[r];
        if (c < 8) orow[r * 88 + 80 + c] = o5[r];
    }
}

extern "C" void kernel_launch(void* const* d_in, const int* in_sizes, int n_in,
                              void* d_out, int out_size, void* d_ws, size_t ws_size,
                              hipStream_t stream) {
    (void)in_sizes; (void)n_in; (void)out_size; (void)d_ws; (void)ws_size;
    tones_v4<<<dim3(NTOK / 64), dim3(TPB), 0, stream>>>(
        (const int*)d_in[0], (const int*)d_in[1], (const float*)d_in[2],
        (const float*)d_in[3],  (const float*)d_in[4],
        (const float*)d_in[5],  (const float*)d_in[6],
        (const float*)d_in[7],  (const float*)d_in[8],
        (const float*)d_in[9],  (const float*)d_in[10],
        (const float*)d_in[11], (const float*)d_in[12],
        (float*)d_out);
}

// Round 5
// 135.600 us; speedup vs baseline: 1.2841x; 1.2841x over previous
//
#include <hip/hip_runtime.h>
#include <stdint.h>

// B=256, T=512, f32 tensors. v5: prep-kernel pre-swizzles weights into d_ws as
// MFMA-fragment bf16 images; main kernel holds B1 (K=224: conv176 + x-onehot16
// + w-onehot16 + bias1 + pad) and B2 (K=64: 48 + bias + pad) entirely in VGPRs.
// Conv is computed directly in A-fragment layout (no LDS round-trip); only the
// GEMM1->GEMM2 H transpose touches LDS (2 KB/wave). No __syncthreads.
#define NTOK (256 * 512)
#define TPB 256

typedef short bf16x8 __attribute__((ext_vector_type(8)));
typedef float f32x4 __attribute__((ext_vector_type(4)));
typedef unsigned short u16;
typedef unsigned int u32;

#define B1_U16 10752   // 28 chunks * 48 cols * 8
#define B2_U16 6144    // 8 chunks * 96 cols * 8

__device__ __forceinline__ u16 f2bf(float f) {
    u32 u = __float_as_uint(f);
    return (u16)((u + 0x7fffu + ((u >> 16) & 1u)) >> 16);  // rne
}

// ---------------- prep: build fragment-ordered bf16 weight images ----------------
__global__ __launch_bounds__(256, 1)
void prep_weights(const float* __restrict__ Wxh, const float* __restrict__ bxh,
                  const float* __restrict__ Wwh, const float* __restrict__ bwh,
                  const float* __restrict__ Wyh, const float* __restrict__ byh,
                  const float* __restrict__ Whl, const float* __restrict__ bhl,
                  u16* __restrict__ ws)
{
    int e = blockIdx.x * 256 + threadIdx.x;
    if (e < B1_U16) {
        int j = e & 7, n = (e >> 3) % 48, kc = e / 384;
        int k = kc * 8 + j;                  // k = 2*d + ch for k<176
        float v;
        if (k < 176)       v = Wyh[n * 176 + (k & 1) * 88 + (k >> 1)];
        else if (k < 192)  v = Wxh[n * 16 + (k - 176)];   // x-onehot rows
        else if (k < 208)  v = Wwh[n * 16 + (k - 192)];   // w-onehot rows
        else if (k == 208) v = bxh[n] + bwh[n] + byh[n];  // bias row
        else               v = 0.0f;
        ws[e] = f2bf(v);
    } else if (e < B1_U16 + B2_U16) {
        int e2 = e - B1_U16;
        int j = e2 & 7, dd = (e2 >> 3) % 96, kc = e2 / 768;
        int k = kc * 8 + j;
        float v = 0.0f;
        if (dd < 88) {
            if (k < 48)       v = Whl[dd * 48 + k];
            else if (k == 48) v = bhl[dd];
        }
        ws[e] = f2bf(v);
    }
}

// ---------------- main ----------------
__global__ __launch_bounds__(256, 2)
void tones_v5(const int* __restrict__ widx, const int* __restrict__ xidx,
              const float* __restrict__ y,
              const float* __restrict__ Wconv, const float* __restrict__ bconv,
              const u16* __restrict__ wsb,
              float* __restrict__ out)
{
    __shared__ __align__(16) u16 sH[4 * 1024];   // per-wave H in A-frag layout (2 KB each)

    const int tid = threadIdx.x;
    const int wave = tid >> 6, lane = tid & 63;
    const int q = lane >> 4, c = lane & 15;

    // ---- B fragments into registers (L2-resident pre-swizzled images) ----
    bf16x8 B1[7][3];
    #pragma unroll
    for (int ks = 0; ks < 7; ks++)
        #pragma unroll
        for (int nt = 0; nt < 3; nt++)
            B1[ks][nt] = *(const bf16x8*)(wsb + ((ks * 4 + q) * 48 + nt * 16 + c) * 8);
    bf16x8 B2[2][6];
    #pragma unroll
    for (int ks = 0; ks < 2; ks++)
        #pragma unroll
        for (int nt = 0; nt < 6; nt++)
            B2[ks][nt] = *(const bf16x8*)(wsb + B1_U16 + ((ks * 4 + q) * 96 + nt * 16 + c) * 8);

    const float wc00 = Wconv[0], wc01 = Wconv[1], wc02 = Wconv[2];
    const float wc10 = Wconv[3], wc11 = Wconv[4], wc12 = Wconv[5];
    const float bc0 = bconv[0], bc1 = bconv[1];

    u16* sW = sH + wave * 1024;

    #pragma unroll 1
    for (int t = 0; t < 4; t++) {
        const int tb = blockIdx.x * 256 + wave * 64 + t * 16;
        const float* yc = y + (size_t)(tb + c) * 88;     // this lane's token row
        const int xv = xidx[tb + c];
        const int wv = widx[tb + c];

        f32x4 h0 = {0, 0, 0, 0}, h1 = {0, 0, 0, 0}, h2 = {0, 0, 0, 0};

        // ---- ks=0..4: conv directly in A-frag layout (d0 = 16s + 4q) ----
        #pragma unroll
        for (int s = 0; s < 5; s++) {
            const int d0 = 16 * s + 4 * q;
            float p0 = (d0 == 0) ? 0.0f : yc[d0 - 1];
            float4 v4 = *(const float4*)(yc + d0);
            float p5 = yc[d0 + 4];                       // d0+4 <= 80 < 88
            float p[6] = {p0, v4.x, v4.y, v4.z, v4.w, p5};
            bf16x8 af;
            #pragma unroll
            for (int i = 0; i < 4; i++) {
                float c0 = fmaf(wc00, p[i], fmaf(wc01, p[i + 1], fmaf(wc02, p[i + 2], bc0)));
                float c1 = fmaf(wc10, p[i], fmaf(wc11, p[i + 1], fmaf(wc12, p[i + 2], bc1)));
                af[2 * i]     = (short)f2bf(fmaxf(c0, 0.0f));
                af[2 * i + 1] = (short)f2bf(fmaxf(c1, 0.0f));
            }
            h0 = __builtin_amdgcn_mfma_f32_16x16x32_bf16(af, B1[s][0], h0, 0, 0, 0);
            h1 = __builtin_amdgcn_mfma_f32_16x16x32_bf16(af, B1[s][1], h1, 0, 0, 0);
            h2 = __builtin_amdgcn_mfma_f32_16x16x32_bf16(af, B1[s][2], h2, 0, 0, 0);
        }
        // ---- ks=5: q<2 -> conv tail (d 80..87); q>=2 -> x-onehot dims (q-2)*8+j ----
        {
            bf16x8 af;
            if (q < 2) {
                const int d0 = 80 + 4 * q;
                float p0 = yc[d0 - 1];
                float4 v4 = *(const float4*)(yc + d0);
                float p5 = (q == 0) ? yc[84] : 0.0f;     // right edge pad at d=87
                float p[6] = {p0, v4.x, v4.y, v4.z, v4.w, p5};
                #pragma unroll
                for (int i = 0; i < 4; i++) {
                    float c0 = fmaf(wc00, p[i], fmaf(wc01, p[i + 1], fmaf(wc02, p[i + 2], bc0)));
                    float c1 = fmaf(wc10, p[i], fmaf(wc11, p[i + 1], fmaf(wc12, p[i + 2], bc1)));
                    af[2 * i]     = (short)f2bf(fmaxf(c0, 0.0f));
                    af[2 * i + 1] = (short)f2bf(fmaxf(c1, 0.0f));
                }
            } else {
                const int base = (q - 2) * 8;
                #pragma unroll
                for (int j = 0; j < 8; j++)
                    af[j] = (short)((base + j == xv) ? 0x3F80 : 0);
            }
            h0 = __builtin_amdgcn_mfma_f32_16x16x32_bf16(af, B1[5][0], h0, 0, 0, 0);
            h1 = __builtin_amdgcn_mfma_f32_16x16x32_bf16(af, B1[5][1], h1, 0, 0, 0);
            h2 = __builtin_amdgcn_mfma_f32_16x16x32_bf16(af, B1[5][2], h2, 0, 0, 0);
        }
        // ---- ks=6: q<2 -> w-onehot dims q*8+j; q==2 -> bias one at j=0; q==3 -> x0 (B rows are 0) ----
        {
            bf16x8 af;
            if (q < 2) {
                const int base = q * 8;
                #pragma unroll
                for (int j = 0; j < 8; j++)
                    af[j] = (short)((base + j == wv) ? 0x3F80 : 0);
            } else {
                #pragma unroll
                for (int j = 0; j < 8; j++)
                    af[j] = (short)((q == 2 && j == 0) ? 0x3F80 : 0);
            }
            h0 = __builtin_amdgcn_mfma_f32_16x16x32_bf16(af, B1[6][0], h0, 0, 0, 0);
            h1 = __builtin_amdgcn_mfma_f32_16x16x32_bf16(af, B1[6][1], h1, 0, 0, 0);
            h2 = __builtin_amdgcn_mfma_f32_16x16x32_bf16(af, B1[6][2], h2, 0, 0, 0);
        }

        // ---- epilogue1: relu -> bf16 H in A-frag layout in per-wave LDS ----
        if (lane < 32) {   // chunk 6: bias-one at k2=48 (j==0); chunk 7: zeros
            uint4 hz = make_uint4((lane < 16) ? 0x3F80u : 0u, 0, 0, 0);
            *(uint4*)(sW + ((6 + (lane >> 4)) * 16 + (lane & 15)) * 8) = hz;
        }
        #pragma unroll
        for (int r = 0; r < 4; r++) {
            const int row = q * 4 + r;   // D row = token index in tile
            sW[((0 + (c >> 3)) * 16 + row) * 8 + (c & 7)] = f2bf(fmaxf(h0[r], 0.0f));
            sW[((2 + (c >> 3)) * 16 + row) * 8 + (c & 7)] = f2bf(fmaxf(h1[r], 0.0f));
            sW[((4 + (c >> 3)) * 16 + row) * 8 + (c & 7)] = f2bf(fmaxf(h2[r], 0.0f));
        }

        // ---- GEMM2: out[16x88] = H[16x64] * B2[64x96] ----
        f32x4 o0 = {0,0,0,0}, o1 = {0,0,0,0}, o2 = {0,0,0,0};
        f32x4 o3 = {0,0,0,0}, o4 = {0,0,0,0}, o5 = {0,0,0,0};
        #pragma unroll
        for (int ks = 0; ks < 2; ks++) {
            bf16x8 a2 = *(const bf16x8*)(sW + ((ks * 4 + q) * 16 + c) * 8);
            o0 = __builtin_amdgcn_mfma_f32_16x16x32_bf16(a2, B2[ks][0], o0, 0, 0, 0);
            o1 = __builtin_amdgcn_mfma_f32_16x16x32_bf16(a2, B2[ks][1], o1, 0, 0, 0);
            o2 = __builtin_amdgcn_mfma_f32_16x16x32_bf16(a2, B2[ks][2], o2, 0, 0, 0);
            o3 = __builtin_amdgcn_mfma_f32_16x16x32_bf16(a2, B2[ks][3], o3, 0, 0, 0);
            o4 = __builtin_amdgcn_mfma_f32_16x16x32_bf16(a2, B2[ks][4], o4, 0, 0, 0);
            o5 = __builtin_amdgcn_mfma_f32_16x16x32_bf16(a2, B2[ks][5], o5, 0, 0, 0);
        }

        // ---- store: D row = token (q*4+r), col d = nt*16 + c ----
        float* orow = out + (size_t)(tb + q * 4) * 88;
        #pragma unroll
        for (int r = 0; r < 4; r++) {
            orow[r * 88 +  0 + c] = o0[r];
            orow[r * 88 + 16 + c] = o1[r];
            orow[r * 88 + 32 + c] = o2[r];
            orow[r * 88 + 48 + c] = o3[r];
            orow[r * 88 + 64 + c] = o4[r];
            if (c < 8) orow[r * 88 + 80 + c] = o5[r];
        }
    }
}

extern "C" void kernel_launch(void* const* d_in, const int* in_sizes, int n_in,
                              void* d_out, int out_size, void* d_ws, size_t ws_size,
                              hipStream_t stream) {
    (void)in_sizes; (void)n_in; (void)out_size; (void)ws_size;
    u16* ws = (u16*)d_ws;
    prep_weights<<<dim3(66), dim3(TPB), 0, stream>>>(
        (const float*)d_in[3],  (const float*)d_in[4],
        (const float*)d_in[5],  (const float*)d_in[6],
        (const float*)d_in[7],  (const float*)d_in[8],
        (const float*)d_in[11], (const float*)d_in[12], ws);
    tones_v5<<<dim3(NTOK / 256), dim3(TPB), 0, stream>>>(
        (const int*)d_in[0], (const int*)d_in[1], (const float*)d_in[2],
        (const float*)d_in[9], (const float*)d_in[10], ws, (float*)d_out);
}